// Round 3
// baseline (1410.399 us; speedup 1.0000x reference)
//
#include <hip/hip_runtime.h>
#include <hip/hip_bf16.h>
#include <math.h>

// Split-bf16 MFMA exact-KNN (K=32) + inverse-squared-distance weighting.
// points:[16384,64] features:[20000,64] targets:[20000] -> out:[16384]
//
// Round 3: block = 16 queries x 8 waves (each wave scans an m-eighth).
// Warm-start rank-select fills top-32 from first chunk (no insert storm);
// cross-wave min-kth threshold prunes inserts 8x; 1024 blocks for occupancy.

#define NQ   16384
#define MM   20000
#define DD   64
#define KK   32
#define MPAD 20032
#define NCH  (MPAD / 64)   // 313
#define NW   8             // waves per block

typedef __attribute__((ext_vector_type(8))) short bf16x8;
typedef __attribute__((ext_vector_type(4))) float f32x4;

// ---- workspace layout (bytes) ----
#define OFF_FH 0
#define SZ_FP  (MPAD * DD * 2)
#define OFF_FL (OFF_FH + SZ_FP)
#define OFF_FN (OFF_FL + SZ_FP)
#define SZ_FN  (MPAD * 4)
#define OFF_QH (OFF_FN + SZ_FN)
#define SZ_QP  (NQ * DD * 2)
#define OFF_QL (OFF_QH + SZ_QP)
#define OFF_QN (OFF_QL + SZ_QP)
#define SZ_QN  (NQ * 4)
#define WS_REQ (OFF_QN + SZ_QN)

__device__ __forceinline__ unsigned int bf16_rne(float x) {
    unsigned int xb = __float_as_uint(x);
    return (xb + 0x7fffu + ((xb >> 16) & 1u)) & 0xffff0000u;
}

__global__ void prep_split(const float* __restrict__ src,
                           unsigned short* __restrict__ ph,
                           unsigned short* __restrict__ pl,
                           float* __restrict__ nrm, int nrows_real) {
    const int e = blockIdx.x * 256 + threadIdx.x;
    const int m = e >> 6;
    const int lane = threadIdx.x & 63;
    const bool real = (m < nrows_real);
    float x = real ? src[e] : 0.f;
    unsigned int hb = bf16_rne(x);
    float xh = __uint_as_float(hb);
    unsigned int lb = bf16_rne(x - xh);
    ph[e] = (unsigned short)(hb >> 16);
    pl[e] = (unsigned short)(lb >> 16);
    float s = x * x;
    #pragma unroll
    for (int o = 32; o >= 1; o >>= 1) s += __shfl_xor(s, o);
    if (lane == 0) nrm[m] = real ? s : __builtin_inff();
}

__global__ __launch_bounds__(512, 4) void knn_mfma(
    const unsigned short* __restrict__ Fh, const unsigned short* __restrict__ Fl,
    const float* __restrict__ fn,
    const unsigned short* __restrict__ Qh, const unsigned short* __restrict__ Ql,
    const float* __restrict__ qn,
    const float* __restrict__ targets, float* __restrict__ out)
{
    // per-wave per-query sorted top-32 (s = fn - 2*dot), stride 33
    __shared__ float top_d[NW][16 * 33];
    __shared__ int   top_i[NW][16 * 33];

    const int tid  = threadIdx.x;
    const int lane = tid & 63;
    const int w    = tid >> 6;            // 0..7 = m-eighth
    const int qbase = blockIdx.x * 16;
    const int q    = lane & 15;           // this lane's query (MFMA col)
    const int hgrp = lane >> 4;           // 0..3 row-group

    // stationary B-operand (Q^T) fragments
    const int qrow = qbase + q;
    const int kof  = hgrp * 8;
    const bf16x8 qh0 = *(const bf16x8*)(Qh + (size_t)qrow * DD + kof);
    const bf16x8 qh1 = *(const bf16x8*)(Qh + (size_t)qrow * DD + kof + 32);
    const bf16x8 ql0 = *(const bf16x8*)(Ql + (size_t)qrow * DD + kof);
    const bf16x8 ql1 = *(const bf16x8*)(Ql + (size_t)qrow * DD + kof + 32);

    float* myTd = &top_d[w][0];
    int*   myTi = &top_i[w][0];

    // ================= warm-start: chunk c0 = w, rank-select 64 -> 32 ======
    {
        const int mbase = w * 64;
        float sv[4][4];
        #pragma unroll
        for (int t = 0; t < 4; ++t) {
            const int frow = mbase + t * 16 + q;
            const unsigned short* ph = Fh + (size_t)frow * DD + kof;
            const unsigned short* pl = Fl + (size_t)frow * DD + kof;
            const bf16x8 Ah0 = *(const bf16x8*)(ph);
            const bf16x8 Ah1 = *(const bf16x8*)(ph + 32);
            const bf16x8 Al0 = *(const bf16x8*)(pl);
            const bf16x8 Al1 = *(const bf16x8*)(pl + 32);
            const f32x4 fnv = *(const f32x4*)(fn + mbase + t * 16 + hgrp * 4);
            f32x4 acc = {0.f, 0.f, 0.f, 0.f};
            acc = __builtin_amdgcn_mfma_f32_16x16x32_bf16(Ah0, qh0, acc, 0, 0, 0);
            acc = __builtin_amdgcn_mfma_f32_16x16x32_bf16(Ah1, qh1, acc, 0, 0, 0);
            acc = __builtin_amdgcn_mfma_f32_16x16x32_bf16(Ah0, ql0, acc, 0, 0, 0);
            acc = __builtin_amdgcn_mfma_f32_16x16x32_bf16(Ah1, ql1, acc, 0, 0, 0);
            acc = __builtin_amdgcn_mfma_f32_16x16x32_bf16(Al0, qh0, acc, 0, 0, 0);
            acc = __builtin_amdgcn_mfma_f32_16x16x32_bf16(Al1, qh1, acc, 0, 0, 0);
            acc = __builtin_amdgcn_mfma_f32_16x16x32_bf16(Al0, ql0, acc, 0, 0, 0);
            acc = __builtin_amdgcn_mfma_f32_16x16x32_bf16(Al1, ql1, acc, 0, 0, 0);
            #pragma unroll
            for (int j = 0; j < 4; ++j) sv[t][j] = fnv[j] - 2.f * acc[j];
        }
        // scratch overlays own wave's top_d/top_i: scr(q,r), q<8 in top_d, q>=8 in top_i
        #pragma unroll
        for (int t = 0; t < 4; ++t)
            #pragma unroll
            for (int j = 0; j < 4; ++j) {
                const int r = t * 16 + hgrp * 4 + j;
                float* p = (q < 8) ? (myTd + q * 66 + r)
                                   : ((float*)myTi + (q - 8) * 66 + r);
                *p = sv[t][j];
            }
        // rank sweep (wave-lockstep: all reads complete before any writes below)
        int rk[4][4];
        #pragma unroll
        for (int t = 0; t < 4; ++t)
            #pragma unroll
            for (int j = 0; j < 4; ++j) rk[t][j] = 0;
        for (int rp = 0; rp < 64; ++rp) {
            const float* p = (q < 8) ? (myTd + q * 66 + rp)
                                     : ((const float*)myTi + (q - 8) * 66 + rp);
            const float vv = *p;
            #pragma unroll
            for (int t = 0; t < 4; ++t)
                #pragma unroll
                for (int j = 0; j < 4; ++j) {
                    const int rown = t * 16 + hgrp * 4 + j;
                    rk[t][j] += (vv < sv[t][j]) || (vv == sv[t][j] && rp < rown);
                }
        }
        #pragma unroll
        for (int t = 0; t < 4; ++t)
            #pragma unroll
            for (int j = 0; j < 4; ++j) {
                const int rr = rk[t][j];
                if (rr < KK) {
                    myTd[q * 33 + rr] = sv[t][j];
                    myTi[q * 33 + rr] = mbase + t * 16 + hgrp * 4 + j;
                }
            }
    }
    __syncthreads();   // all 8 lists warm before cross-wave tau reads

    // ================= main scan =================
    for (int c = w + NW; c < NCH; c += NW) {
        // refresh tau (min of the 8 waves' 32nd values for this lane's query)
        float tau = __builtin_inff();
        #pragma unroll
        for (int ww = 0; ww < NW; ++ww)
            tau = fminf(tau, top_d[ww][q * 33 + 31]);

        const int mbase = c * 64;
        bf16x8 Ah0[4], Ah1[4], Al0[4], Al1[4];
        f32x4  fnv[4];
        #pragma unroll
        for (int t = 0; t < 4; ++t) {
            const int frow = mbase + t * 16 + q;
            const unsigned short* ph = Fh + (size_t)frow * DD + kof;
            const unsigned short* pl = Fl + (size_t)frow * DD + kof;
            Ah0[t] = *(const bf16x8*)(ph);
            Ah1[t] = *(const bf16x8*)(ph + 32);
            Al0[t] = *(const bf16x8*)(pl);
            Al1[t] = *(const bf16x8*)(pl + 32);
            fnv[t] = *(const f32x4*)(fn + mbase + t * 16 + hgrp * 4);
        }

        #pragma unroll
        for (int t = 0; t < 4; ++t) {
            f32x4 acc = {0.f, 0.f, 0.f, 0.f};
            acc = __builtin_amdgcn_mfma_f32_16x16x32_bf16(Ah0[t], qh0, acc, 0, 0, 0);
            acc = __builtin_amdgcn_mfma_f32_16x16x32_bf16(Ah1[t], qh1, acc, 0, 0, 0);
            acc = __builtin_amdgcn_mfma_f32_16x16x32_bf16(Ah0[t], ql0, acc, 0, 0, 0);
            acc = __builtin_amdgcn_mfma_f32_16x16x32_bf16(Ah1[t], ql1, acc, 0, 0, 0);
            acc = __builtin_amdgcn_mfma_f32_16x16x32_bf16(Al0[t], qh0, acc, 0, 0, 0);
            acc = __builtin_amdgcn_mfma_f32_16x16x32_bf16(Al1[t], qh1, acc, 0, 0, 0);
            acc = __builtin_amdgcn_mfma_f32_16x16x32_bf16(Al0[t], ql0, acc, 0, 0, 0);
            acc = __builtin_amdgcn_mfma_f32_16x16x32_bf16(Al1[t], ql1, acc, 0, 0, 0);

            const float s0 = fnv[t][0] - 2.f * acc[0];
            const float s1 = fnv[t][1] - 2.f * acc[1];
            const float s2 = fnv[t][2] - 2.f * acc[2];
            const float s3 = fnv[t][3] - 2.f * acc[3];

            const float mn = fminf(fminf(s0, s1), fminf(s2, s3));
            unsigned long long bal = __ballot(mn < tau);
            const int rbase = mbase + t * 16;
            while (bal) {
                const int src = __builtin_ctzll(bal);
                bal &= bal - 1;
                const int qu   = src & 15;
                const int mrow = rbase + (src >> 4) * 4;
                const float tq = __shfl(tau, qu);
                const float b0 = __shfl(s0, src);
                const float b1 = __shfl(s1, src);
                const float b2 = __shfl(s2, src);
                const float b3 = __shfl(s3, src);
                const float bv[4] = {b0, b1, b2, b3};
                #pragma unroll
                for (int jj = 0; jj < 4; ++jj) {
                    const float val = bv[jj];
                    if (val < tq) {                   // wave-uniform; stale-safe (no-op insert ok)
                        const int mi = mrow + jj;
                        const float cur_d = myTd[qu * 33 + (lane & 31)];
                        const int   cur_i = myTi[qu * 33 + (lane & 31)];
                        float prev_d = __shfl_up(cur_d, 1);
                        int   prev_i = __shfl_up(cur_i, 1);
                        if (lane == 0) prev_d = -__builtin_inff();
                        if (lane < 32 && cur_d > val) {
                            const bool tp = (prev_d > val);
                            myTd[qu * 33 + lane] = tp ? prev_d : val;
                            myTi[qu * 33 + lane] = tp ? prev_i : mi;
                        }
                    }
                }
            }
        }
    }

    __syncthreads();

    // ============ epilogue: 8-way merge by rank, weight, reduce ============
    // wave w handles queries w*2, w*2+1; lane -> list l=lane>>3, slots (lane&7)+{0,8,16,24}
    const int l  = lane >> 3;
    const int sb = lane & 7;
    #pragma unroll
    for (int e = 0; e < 2; ++e) {
        const int qq = w * 2 + e;
        const int qglob = qbase + qq;
        const float qnv = qn[qglob];
        float nume = 0.f, deno = 0.f;
        #pragma unroll
        for (int ss = 0; ss < 4; ++ss) {
            const int slot = sb + ss * 8;
            const float v  = top_d[l][qq * 33 + slot];
            const int   mi = top_i[l][qq * 33 + slot];
            int rank = slot;
            #pragma unroll
            for (int j = 0; j < NW; ++j) {
                if (j == l) continue;
                int cnt = 0;
                #pragma unroll
                for (int st = 32; st >= 1; st >>= 1) {
                    const int t2 = cnt + st;
                    if (t2 <= 32) {
                        const float dj = top_d[j][qq * 33 + t2 - 1];
                        const int   ij = top_i[j][qq * 33 + t2 - 1];
                        if (dj < v || (dj == v && ij < mi)) cnt = t2;
                    }
                }
                rank += cnt;
            }
            if (rank < KK) {
                const float d2 = fmaxf(qnv + v, 0.f);
                const float wv = 1.f / (d2 + 1e-4f);
                nume = fmaf(wv, targets[mi], nume);
                deno += wv;
            }
        }
        #pragma unroll
        for (int o = 32; o >= 1; o >>= 1) {
            nume += __shfl_xor(nume, o);
            deno += __shfl_xor(deno, o);
        }
        if (lane == 0) out[qglob] = nume / fmaxf(deno, 1e-9f);
    }
}

// ---------------- fallback: round-1 exact fp32 vector kernel ----------------
#define BQ 32
#define WQ 8
__global__ __launch_bounds__(256) void hp_knn_kernel(
    const float* __restrict__ points, const float* __restrict__ features,
    const float* __restrict__ targets, float* __restrict__ out)
{
    __shared__ __align__(16) float Qs[BQ][DD];
    __shared__ float qn_s[BQ];
    __shared__ float topd[BQ][KK];
    __shared__ int   topi[BQ][KK];
    const int tid = threadIdx.x, lane = tid & 63, wv = tid >> 6, qb = wv * WQ;
    {
        const float4* src = (const float4*)(points + (size_t)blockIdx.x * BQ * DD);
        float4* dst = (float4*)&Qs[0][0];
        #pragma unroll
        for (int i = 0; i < (BQ * DD / 4) / 256; ++i) dst[tid + i * 256] = src[tid + i * 256];
    }
    for (int i = tid; i < BQ * KK; i += 256) { (&topd[0][0])[i] = __builtin_inff(); (&topi[0][0])[i] = 0; }
    __syncthreads();
    if (tid < BQ) {
        float s = 0.f;
        #pragma unroll
        for (int d = 0; d < DD; ++d) s = fmaf(Qs[tid][d], Qs[tid][d], s);
        qn_s[tid] = s;
    }
    __syncthreads();
    for (int c = 0; c < (MM + 63) / 64; ++c) {
        const int m = c * 64 + lane, mc = (m < MM) ? m : (MM - 1);
        float f[DD];
        const float4* fr = (const float4*)(features + (size_t)mc * DD);
        #pragma unroll
        for (int b = 0; b < DD / 4; ++b) { float4 v = fr[b]; f[4*b]=v.x; f[4*b+1]=v.y; f[4*b+2]=v.z; f[4*b+3]=v.w; }
        float fnv = 0.f;
        #pragma unroll
        for (int d = 0; d < DD; ++d) fnv = fmaf(f[d], f[d], fnv);
        float d2v[WQ];
        #pragma unroll
        for (int qi = 0; qi < WQ; ++qi) {
            const float4* qr = (const float4*)&Qs[qb + qi][0];
            float a0=0,a1=0,a2=0,a3=0;
            #pragma unroll
            for (int b = 0; b < DD / 4; ++b) {
                float4 q4 = qr[b];
                a0 = fmaf(q4.x, f[4*b], a0); a1 = fmaf(q4.y, f[4*b+1], a1);
                a2 = fmaf(q4.z, f[4*b+2], a2); a3 = fmaf(q4.w, f[4*b+3], a3);
            }
            float d2 = fmaxf(qn_s[qb+qi] + fnv - 2.f*((a0+a1)+(a2+a3)), 0.f);
            d2v[qi] = (m < MM) ? d2 : __builtin_inff();
        }
        #pragma unroll
        for (int qi = 0; qi < WQ; ++qi) {
            const int q = qb + qi;
            unsigned long long ball = __ballot(d2v[qi] < topd[q][KK-1]);
            while (ball) {
                const int j = __builtin_ctzll(ball); ball &= ball - 1;
                const float dval = __shfl(d2v[qi], j); const int mval = c * 64 + j;
                if (lane < KK) {
                    const float cur = topd[q][lane];
                    if (cur > dval) {
                        const float pd = (lane > 0) ? topd[q][lane-1] : -1.f;
                        const int   pi = (lane > 0) ? topi[q][lane-1] : 0;
                        const bool tp = (pd > dval);
                        topd[q][lane] = tp ? pd : dval; topi[q][lane] = tp ? pi : mval;
                    }
                }
            }
        }
    }
    #pragma unroll
    for (int qi = 0; qi < WQ; ++qi) {
        const int q = qb + qi;
        float wsum = 0.f, wt = 0.f;
        if (lane < KK) {
            const float ww = 1.f / (topd[q][lane] + 1e-4f);
            wsum = ww; wt = ww * targets[topi[q][lane]];
        }
        #pragma unroll
        for (int o = 32; o >= 1; o >>= 1) { wsum += __shfl_xor(wsum, o); wt += __shfl_xor(wt, o); }
        if (lane == 0) out[(size_t)blockIdx.x * BQ + q] = wt / fmaxf(wsum, 1e-9f);
    }
}

extern "C" void kernel_launch(void* const* d_in, const int* in_sizes, int n_in,
                              void* d_out, int out_size, void* d_ws, size_t ws_size,
                              hipStream_t stream) {
    const float* points   = (const float*)d_in[0];
    const float* features = (const float*)d_in[1];
    const float* targets  = (const float*)d_in[2];
    float* out = (float*)d_out;

    if (ws_size < (size_t)WS_REQ) {
        hp_knn_kernel<<<dim3(NQ / BQ), dim3(256), 0, stream>>>(points, features, targets, out);
        return;
    }
    char* ws = (char*)d_ws;
    unsigned short* Fh = (unsigned short*)(ws + OFF_FH);
    unsigned short* Fl = (unsigned short*)(ws + OFF_FL);
    float*          fn = (float*)(ws + OFF_FN);
    unsigned short* Qh = (unsigned short*)(ws + OFF_QH);
    unsigned short* Ql = (unsigned short*)(ws + OFF_QL);
    float*          qnp= (float*)(ws + OFF_QN);

    prep_split<<<dim3(MPAD * DD / 256), dim3(256), 0, stream>>>(features, Fh, Fl, fn, MM);
    prep_split<<<dim3(NQ * DD / 256),  dim3(256), 0, stream>>>(points,   Qh, Ql, qnp, NQ);
    knn_mfma<<<dim3(NQ / 16), dim3(512), 0, stream>>>(Fh, Fl, fn, Qh, Ql, qnp, targets, out);
}

// Round 4
// 1293.896 us; speedup vs baseline: 1.0900x; 1.0900x over previous
//
#include <hip/hip_runtime.h>
#include <hip/hip_bf16.h>
#include <math.h>

// Split-bf16 MFMA exact-KNN (K=32) + inverse-squared-distance weighting.
// points:[16384,64] features:[20000,64] targets:[20000] -> out:[16384]
//
// Round 4: 512 blocks x 512 thr; 32 q/block = 2 q-groups(16q) x 4 m-quarters.
// Selection: per-wave sorted top-32 in LDS; candidates merged via batched
// 4-value merge-by-rank (1 LDS read + 1 write per pop, ballot-based ranks)
// gated by a register tau (own 32nd, refreshed once per chunk).

#define NQ   16384
#define MM   20000
#define DD   64
#define KK   32
#define MPAD 20032
#define NCH  (MPAD / 64)   // 313
#define NW   8

typedef __attribute__((ext_vector_type(8))) short bf16x8;
typedef __attribute__((ext_vector_type(4))) float f32x4;

// ---- workspace layout (bytes) ----
#define OFF_FH 0
#define SZ_FP  (MPAD * DD * 2)
#define OFF_FL (OFF_FH + SZ_FP)
#define OFF_FN (OFF_FL + SZ_FP)
#define SZ_FN  (MPAD * 4)
#define OFF_QH (OFF_FN + SZ_FN)
#define SZ_QP  (NQ * DD * 2)
#define OFF_QL (OFF_QH + SZ_QP)
#define OFF_QN (OFF_QL + SZ_QP)
#define SZ_QN  (NQ * 4)
#define WS_REQ (OFF_QN + SZ_QN)

__device__ __forceinline__ unsigned int bf16_rne(float x) {
    unsigned int xb = __float_as_uint(x);
    return (xb + 0x7fffu + ((xb >> 16) & 1u)) & 0xffff0000u;
}

__global__ void prep_split(const float* __restrict__ src,
                           unsigned short* __restrict__ ph,
                           unsigned short* __restrict__ pl,
                           float* __restrict__ nrm, int nrows_real) {
    const int e = blockIdx.x * 256 + threadIdx.x;
    const int m = e >> 6;
    const int lane = threadIdx.x & 63;
    const bool real = (m < nrows_real);
    float x = real ? src[e] : 0.f;
    unsigned int hb = bf16_rne(x);
    float xh = __uint_as_float(hb);
    unsigned int lb = bf16_rne(x - xh);
    ph[e] = (unsigned short)(hb >> 16);
    pl[e] = (unsigned short)(lb >> 16);
    float s = x * x;
    #pragma unroll
    for (int o = 32; o >= 1; o >>= 1) s += __shfl_xor(s, o);
    if (lane == 0) nrm[m] = real ? s : __builtin_inff();
}

#define CSWAP(a,b,ia,ib) { if (a > b) { float tf=a; a=b; b=tf; int ti=ia; ia=ib; ib=ti; } }

__global__ __launch_bounds__(512, 4) void knn_mfma(
    const unsigned short* __restrict__ Fh, const unsigned short* __restrict__ Fl,
    const float* __restrict__ fn,
    const unsigned short* __restrict__ Qh, const unsigned short* __restrict__ Ql,
    const float* __restrict__ qn,
    const float* __restrict__ targets, float* __restrict__ out)
{
    __shared__ float top_d[NW][16 * 33];
    __shared__ int   top_i[NW][16 * 33];

    const int tid  = threadIdx.x;
    const int lane = tid & 63;
    const int w    = tid >> 6;          // 0..7
    const int qgrp = w >> 2;            // 0..1 query group
    const int quar = w & 3;             // 0..3 m-quarter
    const int qbase = blockIdx.x * 32 + qgrp * 16;
    const int q    = lane & 15;
    const int hgrp = lane >> 4;

    // init own wave's list
    for (int i = lane; i < 16 * 33; i += 64) {
        top_d[w][i] = __builtin_inff();
        top_i[w][i] = 0;
    }

    // stationary B-operand (Q^T) fragments
    const int qrow = qbase + q;
    const int kof  = hgrp * 8;
    const bf16x8 qh0 = *(const bf16x8*)(Qh + (size_t)qrow * DD + kof);
    const bf16x8 qh1 = *(const bf16x8*)(Qh + (size_t)qrow * DD + kof + 32);
    const bf16x8 ql0 = *(const bf16x8*)(Ql + (size_t)qrow * DD + kof);
    const bf16x8 ql1 = *(const bf16x8*)(Ql + (size_t)qrow * DD + kof + 32);

    float* myTd = &top_d[w][0];
    int*   myTi = &top_i[w][0];

    for (int c = quar; c < NCH; c += 4) {
        const float tau = myTd[q * 33 + 31];   // own-list 32nd (broadcast read)
        const int mbase = c * 64;

        bf16x8 Ah0[4], Ah1[4], Al0[4], Al1[4];
        f32x4  fnv[4];
        #pragma unroll
        for (int t = 0; t < 4; ++t) {
            const int frow = mbase + t * 16 + q;
            const unsigned short* ph = Fh + (size_t)frow * DD + kof;
            const unsigned short* pl = Fl + (size_t)frow * DD + kof;
            Ah0[t] = *(const bf16x8*)(ph);
            Ah1[t] = *(const bf16x8*)(ph + 32);
            Al0[t] = *(const bf16x8*)(pl);
            Al1[t] = *(const bf16x8*)(pl + 32);
            fnv[t] = *(const f32x4*)(fn + mbase + t * 16 + hgrp * 4);
        }

        #pragma unroll
        for (int t = 0; t < 4; ++t) {
            f32x4 acc = {0.f, 0.f, 0.f, 0.f};
            acc = __builtin_amdgcn_mfma_f32_16x16x32_bf16(Ah0[t], qh0, acc, 0, 0, 0);
            acc = __builtin_amdgcn_mfma_f32_16x16x32_bf16(Ah1[t], qh1, acc, 0, 0, 0);
            acc = __builtin_amdgcn_mfma_f32_16x16x32_bf16(Ah0[t], ql0, acc, 0, 0, 0);
            acc = __builtin_amdgcn_mfma_f32_16x16x32_bf16(Ah1[t], ql1, acc, 0, 0, 0);
            acc = __builtin_amdgcn_mfma_f32_16x16x32_bf16(Al0[t], qh0, acc, 0, 0, 0);
            acc = __builtin_amdgcn_mfma_f32_16x16x32_bf16(Al1[t], qh1, acc, 0, 0, 0);
            acc = __builtin_amdgcn_mfma_f32_16x16x32_bf16(Al0[t], ql0, acc, 0, 0, 0);
            acc = __builtin_amdgcn_mfma_f32_16x16x32_bf16(Al1[t], ql1, acc, 0, 0, 0);

            const float s0 = fnv[t][0] - 2.f * acc[0];
            const float s1 = fnv[t][1] - 2.f * acc[1];
            const float s2 = fnv[t][2] - 2.f * acc[2];
            const float s3 = fnv[t][3] - 2.f * acc[3];

            const float mn = fminf(fminf(s0, s1), fminf(s2, s3));
            unsigned long long bal = __ballot(mn < tau);
            const int rbase = mbase + t * 16;

            while (bal) {
                const int src = __builtin_ctzll(bal);
                bal &= bal - 1;
                const int qu   = src & 15;
                const int mrow = rbase + (src >> 4) * 4;

                // broadcast the 4 candidate values; sort (stable: idx asc on ties)
                float v0 = __shfl(s0, src), v1 = __shfl(s1, src);
                float v2 = __shfl(s2, src), v3 = __shfl(s3, src);
                int i0 = mrow, i1 = mrow + 1, i2 = mrow + 2, i3 = mrow + 3;
                CSWAP(v0, v1, i0, i1); CSWAP(v2, v3, i2, i3);
                CSWAP(v0, v2, i0, i2); CSWAP(v1, v3, i1, i3);
                CSWAP(v1, v2, i1, i2);

                const int sl   = lane & 31;
                const int base = qu * 33;
                const float od = myTd[base + sl];
                const int   oi = myTi[base + sl];

                // old element's shift = #new strictly before it
                const int cnt = (int)(v0 < od) + (int)(v1 < od) + (int)(v2 < od) + (int)(v3 < od);
                // new elements' ranks: #old <= v_j (old-before-new on ties) + j
                const int p0 = __popc((unsigned)__ballot(od <= v0));
                const int p1 = __popc((unsigned)__ballot(od <= v1));
                const int p2 = __popc((unsigned)__ballot(od <= v2));
                const int p3 = __popc((unsigned)__ballot(od <= v3));

                const int tdst = sl + cnt;
                if (lane < 32 && tdst < 32) {
                    myTd[base + tdst] = od;
                    myTi[base + tdst] = oi;
                }
                const int r0 = p0 + 0, r1 = p1 + 1, r2 = p2 + 2, r3 = p3 + 3;
                const float wv = (lane == 0) ? v0 : (lane == 1) ? v1 : (lane == 2) ? v2 : v3;
                const int   wi = (lane == 0) ? i0 : (lane == 1) ? i1 : (lane == 2) ? i2 : i3;
                const int   wr = (lane == 0) ? r0 : (lane == 1) ? r1 : (lane == 2) ? r2 : r3;
                if (lane < 4 && wr < 32) {
                    myTd[base + wr] = wv;
                    myTi[base + wr] = wi;
                }
            }
        }
    }

    __syncthreads();

    // ============ epilogue: 4-way merge by rank, weight, reduce ============
    // group g lists = top_d[g*4 + l]; wave w handles 4 queries of its group.
    const int l   = lane >> 4;          // list 0..3 within group
    const int sl2 = lane & 15;
    #pragma unroll
    for (int e = 0; e < 4; ++e) {
        const int qq = quar * 4 + e;            // quar doubles as per-group wave id
        const int qglob = qbase + qq;
        const float qnv = qn[qglob];
        float nume = 0.f, deno = 0.f;
        #pragma unroll
        for (int ss = 0; ss < 2; ++ss) {
            const int slot = sl2 + ss * 16;
            const float v  = top_d[qgrp * 4 + l][qq * 33 + slot];
            const int   mi = top_i[qgrp * 4 + l][qq * 33 + slot];
            int rank = slot;
            #pragma unroll
            for (int jj = 0; jj < 4; ++jj) {
                if (jj == l) continue;
                int cnt = 0;
                #pragma unroll
                for (int st = 32; st >= 1; st >>= 1) {
                    const int t2 = cnt + st;
                    if (t2 <= 32) {
                        const float dj = top_d[qgrp * 4 + jj][qq * 33 + t2 - 1];
                        const int   ij = top_i[qgrp * 4 + jj][qq * 33 + t2 - 1];
                        if (dj < v || (dj == v && ij < mi)) cnt = t2;
                    }
                }
                rank += cnt;
            }
            if (rank < KK) {
                const float d2 = fmaxf(qnv + v, 0.f);
                const float wv = 1.f / (d2 + 1e-4f);
                nume = fmaf(wv, targets[mi], nume);
                deno += wv;
            }
        }
        #pragma unroll
        for (int o = 32; o >= 1; o >>= 1) {
            nume += __shfl_xor(nume, o);
            deno += __shfl_xor(deno, o);
        }
        if (lane == 0) out[qglob] = nume / fmaxf(deno, 1e-9f);
    }
}

// ---------------- fallback: round-1 exact fp32 vector kernel ----------------
#define BQ 32
#define WQ 8
__global__ __launch_bounds__(256) void hp_knn_kernel(
    const float* __restrict__ points, const float* __restrict__ features,
    const float* __restrict__ targets, float* __restrict__ out)
{
    __shared__ __align__(16) float Qs[BQ][DD];
    __shared__ float qn_s[BQ];
    __shared__ float topd[BQ][KK];
    __shared__ int   topi[BQ][KK];
    const int tid = threadIdx.x, lane = tid & 63, wv = tid >> 6, qb = wv * WQ;
    {
        const float4* src = (const float4*)(points + (size_t)blockIdx.x * BQ * DD);
        float4* dst = (float4*)&Qs[0][0];
        #pragma unroll
        for (int i = 0; i < (BQ * DD / 4) / 256; ++i) dst[tid + i * 256] = src[tid + i * 256];
    }
    for (int i = tid; i < BQ * KK; i += 256) { (&topd[0][0])[i] = __builtin_inff(); (&topi[0][0])[i] = 0; }
    __syncthreads();
    if (tid < BQ) {
        float s = 0.f;
        #pragma unroll
        for (int d = 0; d < DD; ++d) s = fmaf(Qs[tid][d], Qs[tid][d], s);
        qn_s[tid] = s;
    }
    __syncthreads();
    for (int c = 0; c < (MM + 63) / 64; ++c) {
        const int m = c * 64 + lane, mc = (m < MM) ? m : (MM - 1);
        float f[DD];
        const float4* fr = (const float4*)(features + (size_t)mc * DD);
        #pragma unroll
        for (int b = 0; b < DD / 4; ++b) { float4 v = fr[b]; f[4*b]=v.x; f[4*b+1]=v.y; f[4*b+2]=v.z; f[4*b+3]=v.w; }
        float fnv = 0.f;
        #pragma unroll
        for (int d = 0; d < DD; ++d) fnv = fmaf(f[d], f[d], fnv);
        float d2v[WQ];
        #pragma unroll
        for (int qi = 0; qi < WQ; ++qi) {
            const float4* qr = (const float4*)&Qs[qb + qi][0];
            float a0=0,a1=0,a2=0,a3=0;
            #pragma unroll
            for (int b = 0; b < DD / 4; ++b) {
                float4 q4 = qr[b];
                a0 = fmaf(q4.x, f[4*b], a0); a1 = fmaf(q4.y, f[4*b+1], a1);
                a2 = fmaf(q4.z, f[4*b+2], a2); a3 = fmaf(q4.w, f[4*b+3], a3);
            }
            float d2 = fmaxf(qn_s[qb+qi] + fnv - 2.f*((a0+a1)+(a2+a3)), 0.f);
            d2v[qi] = (m < MM) ? d2 : __builtin_inff();
        }
        #pragma unroll
        for (int qi = 0; qi < WQ; ++qi) {
            const int q = qb + qi;
            unsigned long long ball = __ballot(d2v[qi] < topd[q][KK-1]);
            while (ball) {
                const int j = __builtin_ctzll(ball); ball &= ball - 1;
                const float dval = __shfl(d2v[qi], j); const int mval = c * 64 + j;
                if (lane < KK) {
                    const float cur = topd[q][lane];
                    if (cur > dval) {
                        const float pd = (lane > 0) ? topd[q][lane-1] : -1.f;
                        const int   pi = (lane > 0) ? topi[q][lane-1] : 0;
                        const bool tp = (pd > dval);
                        topd[q][lane] = tp ? pd : dval; topi[q][lane] = tp ? pi : mval;
                    }
                }
            }
        }
    }
    #pragma unroll
    for (int qi = 0; qi < WQ; ++qi) {
        const int q = qb + qi;
        float wsum = 0.f, wt = 0.f;
        if (lane < KK) {
            const float ww = 1.f / (topd[q][lane] + 1e-4f);
            wsum = ww; wt = ww * targets[topi[q][lane]];
        }
        #pragma unroll
        for (int o = 32; o >= 1; o >>= 1) { wsum += __shfl_xor(wsum, o); wt += __shfl_xor(wt, o); }
        if (lane == 0) out[(size_t)blockIdx.x * BQ + q] = wt / fmaxf(wsum, 1e-9f);
    }
}

extern "C" void kernel_launch(void* const* d_in, const int* in_sizes, int n_in,
                              void* d_out, int out_size, void* d_ws, size_t ws_size,
                              hipStream_t stream) {
    const float* points   = (const float*)d_in[0];
    const float* features = (const float*)d_in[1];
    const float* targets  = (const float*)d_in[2];
    float* out = (float*)d_out;

    if (ws_size < (size_t)WS_REQ) {
        hp_knn_kernel<<<dim3(NQ / BQ), dim3(256), 0, stream>>>(points, features, targets, out);
        return;
    }
    char* ws = (char*)d_ws;
    unsigned short* Fh = (unsigned short*)(ws + OFF_FH);
    unsigned short* Fl = (unsigned short*)(ws + OFF_FL);
    float*          fn = (float*)(ws + OFF_FN);
    unsigned short* Qh = (unsigned short*)(ws + OFF_QH);
    unsigned short* Ql = (unsigned short*)(ws + OFF_QL);
    float*          qnp= (float*)(ws + OFF_QN);

    prep_split<<<dim3(MPAD * DD / 256), dim3(256), 0, stream>>>(features, Fh, Fl, fn, MM);
    prep_split<<<dim3(NQ * DD / 256),  dim3(256), 0, stream>>>(points,   Qh, Ql, qnp, NQ);
    knn_mfma<<<dim3(NQ / 32), dim3(512), 0, stream>>>(Fh, Fl, fn, Qh, Ql, qnp, targets, out);
}